// Round 12
// baseline (450.369 us; speedup 1.0000x reference)
//
#include <hip/hip_runtime.h>
#include <hip/hip_bf16.h>

typedef __attribute__((ext_vector_type(8))) __bf16 bf16x8;
typedef __attribute__((ext_vector_type(4))) float f32x4;
typedef __attribute__((ext_vector_type(16))) float f32x16;
typedef __attribute__((ext_vector_type(4))) unsigned short ushort4v;
typedef __attribute__((ext_vector_type(8))) unsigned short ushort8v;
typedef unsigned short u16;

// ---------- helpers ----------
__device__ __forceinline__ u16 f2bf_bits(float f) {
    union { float f; unsigned int u; } x; x.f = f;
    unsigned int r = x.u + 0x7FFFu + ((x.u >> 16) & 1u);   // RNE
    return (u16)(r >> 16);
}

__device__ __forceinline__ void gload_lds16(const void* g, void* l) {
    __builtin_amdgcn_global_load_lds(
        (const __attribute__((address_space(1))) void*)g,
        (__attribute__((address_space(3))) void*)l, 16, 0, 0);
}

#define BARRIER()  __builtin_amdgcn_s_barrier()
#define LGKM0()    asm volatile("s_waitcnt lgkmcnt(0)" ::: "memory")
#define VMW8()     asm volatile("s_waitcnt vmcnt(8)" ::: "memory")

// ---------- f32 -> bf16 convert (contiguous) ----------
__global__ void cvt4(const float* __restrict__ in, u16* __restrict__ out, int n) {
    int i = (blockIdx.x * 256 + threadIdx.x) << 2;
    if (i >= n) return;
    f32x4 v = *reinterpret_cast<const f32x4*>(in + i);
    ushort4v o;
    o.x = f2bf_bits(v.x); o.y = f2bf_bits(v.y);
    o.z = f2bf_bits(v.z); o.w = f2bf_bits(v.w);
    *reinterpret_cast<ushort4v*>(out + i) = o;
}

// ---------- f32 (R x C) -> bf16 transposed (C x R), 64x64 tiles ----------
__global__ __launch_bounds__(256)
void transpose_cvt64(const float* __restrict__ in, u16* __restrict__ out,
                     int R, int C) {
    __shared__ float t[64][67];
    const int c0 = blockIdx.x << 6;
    const int r0 = blockIdx.y << 6;
    const int tx = threadIdx.x & 15;
    const int ty = threadIdx.x >> 4;
    #pragma unroll
    for (int j = 0; j < 4; ++j) {
        f32x4 v = *reinterpret_cast<const f32x4*>(
            &in[(size_t)(r0 + ty + 16 * j) * C + c0 + (tx << 2)]);
        *reinterpret_cast<f32x4*>(&t[ty + 16 * j][tx << 2]) = v;
    }
    __syncthreads();
    const int orow8 = threadIdx.x >> 3;        // 0..31
    const int seg8  = (threadIdx.x & 7) << 3;  // 0..56
    #pragma unroll
    for (int p = 0; p < 2; ++p) {
        const int oc = orow8 + (p << 5);
        ushort8v o;
        #pragma unroll
        for (int i = 0; i < 8; ++i)
            o[i] = f2bf_bits(t[seg8 + i][oc]);
        *reinterpret_cast<ushort8v*>(&out[(size_t)(c0 + oc) * R + r0 + seg8]) = o;
    }
}

// ---------- split-K reduce + bias + reparameterization (fused) ----------
__global__ __launch_bounds__(256)
void zred(const float* __restrict__ P, const float* __restrict__ be2,
          const float* __restrict__ eps, float* __restrict__ mu,
          float* __restrict__ lv, u16* __restrict__ zs) {
    const int i = blockIdx.x * 256 + threadIdx.x;      // over 4096*512/4
    const int r = i >> 7;
    const int c4 = (i & 127) << 2;
    const size_t base = (size_t)r * 1024 + c4;
    const size_t PS = (size_t)4096 * 1024;

    f32x4 m = *reinterpret_cast<const f32x4*>(P + base);
    f32x4 l = *reinterpret_cast<const f32x4*>(P + base + 512);
    #pragma unroll
    for (int s = 1; s < 4; ++s) {
        m += *reinterpret_cast<const f32x4*>(P + s * PS + base);
        l += *reinterpret_cast<const f32x4*>(P + s * PS + base + 512);
    }
    m += *reinterpret_cast<const f32x4*>(be2 + c4);
    l += *reinterpret_cast<const f32x4*>(be2 + 512 + c4);

    const size_t ob = (size_t)r * 512 + c4;
    *reinterpret_cast<f32x4*>(mu + ob) = m;
    *reinterpret_cast<f32x4*>(lv + ob) = l;

    f32x4 e = *reinterpret_cast<const f32x4*>(eps + ob);
    ushort4v o;
    o.x = f2bf_bits(m.x + __expf(0.5f * l.x) * e.x);
    o.y = f2bf_bits(m.y + __expf(0.5f * l.y) * e.y);
    o.z = f2bf_bits(m.z + __expf(0.5f * l.z) * e.z);
    o.w = f2bf_bits(m.w + __expf(0.5f * l.w) * e.w);
    *reinterpret_cast<ushort4v*>(zs + ob) = o;
}

// ---------- 256x256 8-phase GEMM (r7 schedule), 32x32x16 MFMA ----------
// Subtiled-LINEAR LDS layout, no swizzle: each 16KB half is organized as
// [subtile(32 rows)][kstep s][khalf][row16B] so every fragment read is
// base + lane*16 — identical address pattern to the gload_lds writes
// (measured conflict-free in r9). Stage source decodes the permutation:
//   lane tid covers LDS byte tid*16 (+chunk*8192):
//     row   = ((tid>>8)&1)*32 + (tid&31)
//     kelem = ((tid>>6)&3)*16 + ((tid>>5)&1)*8
// MFMA 32x32x16 frag: lane l <-> row l&31, k-half l>>5 (verified r10/r11).
template<int MODE>
__global__ __launch_bounds__(512, 2)
void gemm256(const u16* __restrict__ A, const u16* __restrict__ Bt,
             const float* __restrict__ bias,
             u16* __restrict__ obf, float* __restrict__ of32,
             int M, int N, int K, int ntiles)
{
    extern __shared__ char lds[];
    const int tid  = threadIdx.x;
    const int lane = tid & 63;
    const int w    = tid >> 6;
    const int wr   = w >> 2;
    const int wc   = w & 3;

    int bid = blockIdx.x;
    int sid = 0;
    int nwg = gridDim.x;
    if (MODE == 3) { sid = bid & 3; bid >>= 2; nwg >>= 2; }
    const int cpx = nwg >> 3;
    bid = (bid & 7) * cpx + (bid >> 3);
    const int nbx  = N >> 8;
    const int brow = (bid / nbx) << 8;
    const int bcol = (bid % nbx) << 8;
    const int kbase = (MODE == 3) ? sid * ntiles : 0;
    float* pout = (MODE == 3) ? of32 + (size_t)sid * M * N : of32;

    // stage-source decode for subtiled-linear layout
    const int arow  = (((tid >> 8) & 1) << 5) + (tid & 31);
    const int kelem = (((tid >> 6) & 3) << 4) + (((tid >> 5) & 1) << 3);
    const size_t aoff = (size_t)(brow + arow) * K + kelem;
    const size_t boff = (size_t)(bcol + arow) * K + kelem;
    const size_t rowK64 = (size_t)64 * K;
    const int wave1024 = w << 10;

    // read-side bases (all reads are base + lane*16)
    const int lane16 = lane << 4;
    const int regA = wr << 14;                    // wave's 128-row A half
    const int regB = 32768 + ((wc >> 1) << 14);   // wave-pair's 128-col B half
    const int subB = (wc & 1) << 1;               // 64-col quarter -> subtile pair

    bf16x8 aa[2][4];     // 2 mt x 4 k-steps
    bf16x8 b0f[4];       // nt=0, 4 k-steps
    bf16x8 b1f[4];       // nt=1
    f32x16 acc[4][2];    // 4 mt x 2 nt
    #pragma unroll
    for (int mt = 0; mt < 4; ++mt)
        #pragma unroll
        for (int nt = 0; nt < 2; ++nt)
            acc[mt][nt] = (f32x16)(0.0f);

#define STAGE_A(buf, h, kt) do { \
    const u16* _s = A + aoff + (size_t)(h) * 128 * K + (size_t)(kt) * 64; \
    gload_lds16(_s,          lds + ((buf) << 16) + ((h) << 14) + wave1024); \
    gload_lds16(_s + rowK64, lds + ((buf) << 16) + ((h) << 14) + 8192 + wave1024); \
} while (0)

#define STAGE_B(buf, h, kt) do { \
    const u16* _s = Bt + boff + (size_t)(h) * 128 * K + (size_t)(kt) * 64; \
    gload_lds16(_s,          lds + ((buf) << 16) + 32768 + ((h) << 14) + wave1024); \
    gload_lds16(_s + rowK64, lds + ((buf) << 16) + 32768 + ((h) << 14) + 8192 + wave1024); \
} while (0)

#define READ_A32(buf, g) do { \
    _Pragma("unroll") \
    for (int mt = 0; mt < 2; ++mt) { \
        const int _b = ((buf) << 16) + regA + ((((g) << 1) + mt) << 12) + lane16; \
        _Pragma("unroll") \
        for (int s = 0; s < 4; ++s) \
            aa[mt][s] = *reinterpret_cast<const bf16x8*>(lds + _b + (s << 10)); \
    } \
} while (0)

#define READ_B32(buf, bf, nt) do { \
    const int _b = ((buf) << 16) + regB + ((subB + (nt)) << 12) + lane16; \
    _Pragma("unroll") \
    for (int s = 0; s < 4; ++s) \
        bf[s] = *reinterpret_cast<const bf16x8*>(lds + _b + (s << 10)); \
} while (0)

#define MM32(bf, g, nt) do { \
    __builtin_amdgcn_s_setprio(1); \
    _Pragma("unroll") \
    for (int s = 0; s < 4; ++s) \
        _Pragma("unroll") \
        for (int mt = 0; mt < 2; ++mt) \
            acc[((g) << 1) + mt][nt] = __builtin_amdgcn_mfma_f32_32x32x16_bf16( \
                aa[mt][s], bf[s], acc[((g) << 1) + mt][nt], 0, 0, 0); \
    __builtin_amdgcn_s_setprio(0); \
} while (0)

    const int NIT = ntiles >> 1;   // 2 K-tiles of 64 per iteration

    // ---- prologue: tile kbase -> buf0, kbase+1 -> buf1 ----
    STAGE_A(0, 0, kbase); STAGE_A(0, 1, kbase); STAGE_B(0, 0, kbase); STAGE_B(0, 1, kbase);
    STAGE_A(1, 0, kbase + 1); STAGE_A(1, 1, kbase + 1); STAGE_B(1, 0, kbase + 1); STAGE_B(1, 1, kbase + 1);
    VMW8(); BARRIER();
    READ_A32(0, 0); READ_B32(0, b0f, 0);       // ph1 operands

    for (int it = 0; it < NIT; ++it) {
        const int tn0r = 2 * it + 2;
        const int tn1r = 2 * it + 3;
        const int tn0 = kbase + (tn0r < ntiles ? tn0r : ntiles - 1);  // dead-stage clamp
        const int tn1 = kbase + (tn1r < ntiles ? tn1r : ntiles - 1);

        // ph1
        BARRIER(); LGKM0();
        MM32(b0f, 0, 0);
        READ_B32(0, b1f, 1);

        // ph2
        BARRIER(); LGKM0();
        STAGE_B(0, 0, tn0);            // B0 last read-issue: prev ph8
        MM32(b1f, 0, 1);
        READ_A32(0, 1);

        // ph3
        BARRIER(); LGKM0();
        STAGE_B(0, 1, tn0);            // B1 last read-issue: ph1
        MM32(b1f, 1, 1);

        // ph4
        BARRIER(); LGKM0();
        STAGE_A(0, 0, tn0); STAGE_A(0, 1, tn0);  // A last read-issue: ph2
        MM32(b0f, 1, 0);
        VMW8();                        // drains prev-iter buf1 stages (lead 4 phases)
        READ_A32(1, 0); READ_B32(1, b0f, 0);

        // ph5
        BARRIER(); LGKM0();
        MM32(b0f, 0, 0);
        READ_B32(1, b1f, 1);

        // ph6
        BARRIER(); LGKM0();
        STAGE_B(1, 0, tn1);
        MM32(b1f, 0, 1);
        READ_A32(1, 1);

        // ph7
        BARRIER(); LGKM0();
        STAGE_B(1, 1, tn1);
        MM32(b1f, 1, 1);

        // ph8
        BARRIER(); LGKM0();
        STAGE_A(1, 0, tn1); STAGE_A(1, 1, tn1);
        MM32(b0f, 1, 0);
        VMW8();                        // drains this-iter buf0 stages (lead 4 phases)
        READ_A32(0, 0); READ_B32(0, b0f, 0);
    }

    // ---- epilogue (32x32 C layout: col=lane&31, row=(r&3)+8*(r>>2)+4*(lane>>5)) ----
    float bb2[2];
    #pragma unroll
    for (int nt = 0; nt < 2; ++nt)
        bb2[nt] = (MODE == 3) ? 0.0f
                              : bias[bcol + (wc << 6) + (nt << 5) + (lane & 31)];

    const int erow = brow + (wr << 7) + ((lane >> 5) << 2);
    const int ecol = bcol + (wc << 6) + (lane & 31);

    #pragma unroll
    for (int mt = 0; mt < 4; ++mt) {
        #pragma unroll
        for (int r = 0; r < 16; ++r) {
            const int row = erow + (mt << 5) + (r & 3) + ((r >> 2) << 3);
            #pragma unroll
            for (int nt = 0; nt < 2; ++nt) {
                const int c = ecol + (nt << 5);
                float v = acc[mt][nt][r] + bb2[nt];
                if (MODE == 0) {
                    v = v > 0.0f ? v : 0.0f;
                    obf[(size_t)row * N + c] = f2bf_bits(v);
                } else {
                    pout[(size_t)row * N + c] = v;
                }
            }
        }
    }
#undef STAGE_A
#undef STAGE_B
#undef READ_A32
#undef READ_B32
#undef MM32
}

// ---------- launch ----------
extern "C" void kernel_launch(void* const* d_in, const int* in_sizes, int n_in,
                              void* d_out, int out_size, void* d_ws, size_t ws_size,
                              hipStream_t stream) {
    const float* x   = (const float*)d_in[0];
    const float* We1 = (const float*)d_in[1];
    const float* be1 = (const float*)d_in[2];
    const float* We2 = (const float*)d_in[3];
    const float* be2 = (const float*)d_in[4];
    const float* Wd1 = (const float*)d_in[5];
    const float* bd1 = (const float*)d_in[6];
    const float* Wd2 = (const float*)d_in[7];
    const float* bd2 = (const float*)d_in[8];
    const float* eps = (const float*)d_in[9];

    const int B = 4096, D = 4096, H = 4096, LAT = 512;

    // workspace layout (lifetimes traced, same as round 9):
    //   [0, 33.5M)      xb (dead after G1) -> partials p0,p1 -> hd
    //   [33.5M, 67.1M)  w1t (dead after G1) -> partials p2,p3
    //   [67.1M, 75.5M)  w2t  [75.5M, 79.7M) w3t  [79.7M, 113.2M) w4t
    //   [113.2M,146.8M) h (dead after z-GEMM) -> zs at its start
    char* ws = (char*)d_ws;
    u16*   xb   = (u16*)(ws);
    u16*   w1t  = (u16*)(ws + 33554432);
    u16*   w2t  = (u16*)(ws + 67108864);
    u16*   w3t  = (u16*)(ws + 75497472);
    u16*   w4t  = (u16*)(ws + 79691776);
    u16*   h    = (u16*)(ws + 113246208);
    float* part = (float*)(ws);                 // 4 x (4096x1024) f32
    u16*   zs   = (u16*)(ws + 113246208);       // over dead h
    u16*   hd   = (u16*)(ws);                   // over dead partials

    float* recon = (float*)d_out;
    float* mu    = recon + (size_t)B * D;
    float* lv    = mu + (size_t)B * LAT;

    hipFuncSetAttribute(reinterpret_cast<const void*>(gemm256<0>),
                        hipFuncAttributeMaxDynamicSharedMemorySize, 131072);
    hipFuncSetAttribute(reinterpret_cast<const void*>(gemm256<1>),
                        hipFuncAttributeMaxDynamicSharedMemorySize, 131072);
    hipFuncSetAttribute(reinterpret_cast<const void*>(gemm256<3>),
                        hipFuncAttributeMaxDynamicSharedMemorySize, 131072);

    cvt4<<<(B * D / 4 + 255) / 256, 256, 0, stream>>>(x, xb, B * D);
    transpose_cvt64<<<dim3(H / 64, D / 64), 256, 0, stream>>>(We1, w1t, D, H);
    transpose_cvt64<<<dim3(2 * LAT / 64, H / 64), 256, 0, stream>>>(We2, w2t, H, 2 * LAT);
    transpose_cvt64<<<dim3(H / 64, LAT / 64), 256, 0, stream>>>(Wd1, w3t, LAT, H);
    transpose_cvt64<<<dim3(D / 64, H / 64), 256, 0, stream>>>(Wd2, w4t, H, D);

    // G1: h = relu(x @ We1 + be1)    M=B, N=H, K=D, 64 tiles
    gemm256<0><<<(B / 256) * (H / 256), 512, 131072, stream>>>(
        xb, w1t, be1, h, nullptr, B, H, D, D / 64);
    // z split-K=4: partials = h @ We2 (16 tiles per sid)
    gemm256<3><<<(B / 256) * (2 * LAT / 256) * 4, 512, 131072, stream>>>(
        h, w2t, nullptr, nullptr, part, B, 2 * LAT, H, (H / 64) / 4);
    // reduce + bias + sampler
    zred<<<(B * LAT / 4) / 256, 256, 0, stream>>>(part, be2, eps, mu, lv, zs);
    // G3: hd = relu(zs @ Wd1 + bd1)  M=B, N=H, K=LAT, 8 tiles
    gemm256<0><<<(B / 256) * (H / 256), 512, 131072, stream>>>(
        zs, w3t, bd1, hd, nullptr, B, H, LAT, LAT / 64);
    // G5: recon = hd @ Wd2 + bd2     M=B, N=D, K=H, 64 tiles
    gemm256<1><<<(B / 256) * (D / 256), 512, 131072, stream>>>(
        hd, w4t, bd2, nullptr, recon, B, D, H, H / 64);
}

// Round 13
// 354.885 us; speedup vs baseline: 1.2691x; 1.2691x over previous
//
#include <hip/hip_runtime.h>
#include <hip/hip_bf16.h>

typedef __attribute__((ext_vector_type(8))) __bf16 bf16x8;
typedef __attribute__((ext_vector_type(4))) float f32x4;
typedef __attribute__((ext_vector_type(4))) unsigned short ushort4v;
typedef __attribute__((ext_vector_type(8))) unsigned short ushort8v;
typedef unsigned short u16;

// ---------- helpers ----------
__device__ __forceinline__ u16 f2bf_bits(float f) {
    union { float f; unsigned int u; } x; x.f = f;
    unsigned int r = x.u + 0x7FFFu + ((x.u >> 16) & 1u);   // RNE
    return (u16)(r >> 16);
}

__device__ __forceinline__ void gload_lds16(const void* g, void* l) {
    __builtin_amdgcn_global_load_lds(
        (const __attribute__((address_space(1))) void*)g,
        (__attribute__((address_space(3))) void*)l, 16, 0, 0);
}

#define BARRIER()  __builtin_amdgcn_s_barrier()
#define LGKM0()    asm volatile("s_waitcnt lgkmcnt(0)" ::: "memory")
#define VMW8()     asm volatile("s_waitcnt vmcnt(8)" ::: "memory")

// ---------- fused preprocessing: x cvt + 4 weight transpose-cvts ----------
// One launch; 1-D grid partitioned by block ranges. Bodies identical to the
// proven cvt4 / transpose_cvt64 (ushort8 output variant).
__global__ __launch_bounds__(256)
void prep(const float* __restrict__ x,   u16* __restrict__ xb,
          const float* __restrict__ We1, u16* __restrict__ w1t,
          const float* __restrict__ We2, u16* __restrict__ w2t,
          const float* __restrict__ Wd1, u16* __restrict__ w3t,
          const float* __restrict__ Wd2, u16* __restrict__ w4t) {
    int bid = blockIdx.x;

    if (bid >= 9728) {                       // ---- cvt region: x -> xb (16M elems)
        const int i = ((bid - 9728) << 10) + ((int)threadIdx.x << 2);
        f32x4 v = *reinterpret_cast<const f32x4*>(x + i);
        ushort4v o;
        o.x = f2bf_bits(v.x); o.y = f2bf_bits(v.y);
        o.z = f2bf_bits(v.z); o.w = f2bf_bits(v.w);
        *reinterpret_cast<ushort4v*>(xb + i) = o;
        return;
    }

    // ---- transpose regions ----
    const float* in; u16* out; int R, C, bx, by;
    if (bid < 4096)      { in = We1; out = w1t; R = 4096; C = 4096; bx = bid & 63; by = bid >> 6; }
    else if (bid < 5120) { bid -= 4096; in = We2; out = w2t; R = 4096; C = 1024; bx = bid & 15; by = bid >> 4; }
    else if (bid < 5632) { bid -= 5120; in = Wd1; out = w3t; R = 512;  C = 4096; bx = bid & 63; by = bid >> 6; }
    else                 { bid -= 5632; in = Wd2; out = w4t; R = 4096; C = 4096; bx = bid & 63; by = bid >> 6; }

    __shared__ float t[64][67];
    const int c0 = bx << 6;
    const int r0 = by << 6;
    const int tx = threadIdx.x & 15;
    const int ty = threadIdx.x >> 4;
    #pragma unroll
    for (int j = 0; j < 4; ++j) {
        f32x4 v = *reinterpret_cast<const f32x4*>(
            &in[(size_t)(r0 + ty + 16 * j) * C + c0 + (tx << 2)]);
        *reinterpret_cast<f32x4*>(&t[ty + 16 * j][tx << 2]) = v;
    }
    __syncthreads();
    const int orow8 = threadIdx.x >> 3;        // 0..31
    const int seg8  = (threadIdx.x & 7) << 3;  // 0..56
    #pragma unroll
    for (int p = 0; p < 2; ++p) {
        const int oc = orow8 + (p << 5);
        ushort8v o;
        #pragma unroll
        for (int i = 0; i < 8; ++i)
            o[i] = f2bf_bits(t[seg8 + i][oc]);
        *reinterpret_cast<ushort8v*>(&out[(size_t)(c0 + oc) * R + r0 + seg8]) = o;
    }
}

// ---------- split-K reduce + bias + reparameterization (fused) ----------
__global__ __launch_bounds__(256)
void zred(const float* __restrict__ P, const float* __restrict__ be2,
          const float* __restrict__ eps, float* __restrict__ mu,
          float* __restrict__ lv, u16* __restrict__ zs) {
    const int i = blockIdx.x * 256 + threadIdx.x;      // over 4096*512/4
    const int r = i >> 7;
    const int c4 = (i & 127) << 2;
    const size_t base = (size_t)r * 1024 + c4;
    const size_t PS = (size_t)4096 * 1024;

    f32x4 m = *reinterpret_cast<const f32x4*>(P + base);
    f32x4 l = *reinterpret_cast<const f32x4*>(P + base + 512);
    #pragma unroll
    for (int s = 1; s < 4; ++s) {
        m += *reinterpret_cast<const f32x4*>(P + s * PS + base);
        l += *reinterpret_cast<const f32x4*>(P + s * PS + base + 512);
    }
    m += *reinterpret_cast<const f32x4*>(be2 + c4);
    l += *reinterpret_cast<const f32x4*>(be2 + 512 + c4);

    const size_t ob = (size_t)r * 512 + c4;
    *reinterpret_cast<f32x4*>(mu + ob) = m;
    *reinterpret_cast<f32x4*>(lv + ob) = l;

    f32x4 e = *reinterpret_cast<const f32x4*>(eps + ob);
    ushort4v o;
    o.x = f2bf_bits(m.x + __expf(0.5f * l.x) * e.x);
    o.y = f2bf_bits(m.y + __expf(0.5f * l.y) * e.y);
    o.z = f2bf_bits(m.z + __expf(0.5f * l.z) * e.z);
    o.w = f2bf_bits(m.w + __expf(0.5f * l.w) * e.w);
    *reinterpret_cast<ushort4v*>(zs + ob) = o;
}

// ---------- 256x256 8-phase GEMM, single-barrier phases (r9-exact, 16x16x32) ----------
// MODE 0: relu->bf16 obf. MODE 1: f32 of32. MODE 3: split-K f32 partial, no bias.
template<int MODE>
__global__ __launch_bounds__(512, 2)
void gemm256(const u16* __restrict__ A, const u16* __restrict__ Bt,
             const float* __restrict__ bias,
             u16* __restrict__ obf, float* __restrict__ of32,
             int M, int N, int K, int ntiles)
{
    extern __shared__ char lds[];
    const int tid  = threadIdx.x;
    const int lane = tid & 63;
    const int w    = tid >> 6;
    const int wr   = w >> 2;
    const int wc   = w & 3;

    int bid = blockIdx.x;
    int sid = 0;
    int nwg = gridDim.x;
    if (MODE == 3) { sid = bid & 3; bid >>= 2; nwg >>= 2; }
    const int cpx = nwg >> 3;
    bid = (bid & 7) * cpx + (bid >> 3);
    const int nbx  = N >> 8;
    const int brow = (bid / nbx) << 8;
    const int bcol = (bid % nbx) << 8;
    const int kbase = (MODE == 3) ? sid * ntiles : 0;
    float* pout = (MODE == 3) ? of32 + (size_t)sid * M * N : of32;

    const int srow  = tid >> 3;
    const int scole = (((tid & 7) ^ (srow & 7)) << 4) >> 1;
    const size_t aoff = (size_t)(brow + srow) * K + scole;
    const size_t boff = (size_t)(bcol + srow) * K + scole;
    const size_t rowK64 = (size_t)64 * K;
    const int wave1024 = w << 10;

    const int lo16 = (lane >> 4) << 4;
    const int swzm = (lane & 7) << 4;
    const int low0 = lo16 ^ swzm;
    const int low1 = (64 | lo16) ^ swzm;
    const int rA   = (lane & 15) << 7;
    const int rB   = ((((wc & 1) << 6) | (lane & 15)) << 7);
    const int regA = wr << 14;
    const int regB = 32768 + ((wc >> 1) << 14);

    bf16x8 a[4][2];
    bf16x8 b0[2][2];
    bf16x8 b1[2][2];
    f32x4 acc[8][4];
    #pragma unroll
    for (int m = 0; m < 8; ++m)
        #pragma unroll
        for (int n = 0; n < 4; ++n)
            acc[m][n] = (f32x4)(0.0f);

#define STAGE_A(buf, h, kt) do { \
    const u16* _s = A + aoff + (size_t)(h) * 128 * K + (size_t)(kt) * 64; \
    gload_lds16(_s,          lds + ((buf) << 16) + ((h) << 14) + wave1024); \
    gload_lds16(_s + rowK64, lds + ((buf) << 16) + ((h) << 14) + 8192 + wave1024); \
} while (0)

#define STAGE_B(buf, h, kt) do { \
    const u16* _s = Bt + boff + (size_t)(h) * 128 * K + (size_t)(kt) * 64; \
    gload_lds16(_s,          lds + ((buf) << 16) + 32768 + ((h) << 14) + wave1024); \
    gload_lds16(_s + rowK64, lds + ((buf) << 16) + 32768 + ((h) << 14) + 8192 + wave1024); \
} while (0)

#define READ_A(buf, g) do { \
    _Pragma("unroll") \
    for (int m = 0; m < 4; ++m) { \
        const int _b = ((buf) << 16) + regA + rA + ((((g) << 2) + m) << 11); \
        a[m][0] = *reinterpret_cast<const bf16x8*>(lds + _b + low0); \
        a[m][1] = *reinterpret_cast<const bf16x8*>(lds + _b + low1); \
    } \
} while (0)

#define READ_B0(buf) do { \
    _Pragma("unroll") \
    for (int n = 0; n < 2; ++n) { \
        const int _b = ((buf) << 16) + regB + rB + (n << 11); \
        b0[n][0] = *reinterpret_cast<const bf16x8*>(lds + _b + low0); \
        b0[n][1] = *reinterpret_cast<const bf16x8*>(lds + _b + low1); \
    } \
} while (0)

#define READ_B1(buf) do { \
    _Pragma("unroll") \
    for (int n = 0; n < 2; ++n) { \
        const int _b = ((buf) << 16) + regB + rB + ((n + 2) << 11); \
        b1[n][0] = *reinterpret_cast<const bf16x8*>(lds + _b + low0); \
        b1[n][1] = *reinterpret_cast<const bf16x8*>(lds + _b + low1); \
    } \
} while (0)

#define MM(bx, mb, nb) do { \
    __builtin_amdgcn_s_setprio(1); \
    _Pragma("unroll") \
    for (int m = 0; m < 4; ++m) \
        _Pragma("unroll") \
        for (int n = 0; n < 2; ++n) \
            _Pragma("unroll") \
            for (int s = 0; s < 2; ++s) \
                acc[(mb) + m][(nb) + n] = __builtin_amdgcn_mfma_f32_16x16x32_bf16( \
                    a[m][s], bx[n][s], acc[(mb) + m][(nb) + n], 0, 0, 0); \
    __builtin_amdgcn_s_setprio(0); \
} while (0)

    const int NIT = ntiles >> 1;   // 2 K-tiles of 64 per iteration

    // ---- prologue: tile kbase -> buf0, kbase+1 -> buf1 ----
    STAGE_A(0, 0, kbase); STAGE_A(0, 1, kbase); STAGE_B(0, 0, kbase); STAGE_B(0, 1, kbase);
    STAGE_A(1, 0, kbase + 1); STAGE_A(1, 1, kbase + 1); STAGE_B(1, 0, kbase + 1); STAGE_B(1, 1, kbase + 1);
    VMW8(); BARRIER();
    READ_A(0, 0); READ_B0(0);          // ph1 operands

    for (int it = 0; it < NIT; ++it) {
        const int tn0r = 2 * it + 2;
        const int tn1r = 2 * it + 3;
        const int tn0 = kbase + (tn0r < ntiles ? tn0r : ntiles - 1);  // dead-stage clamp
        const int tn1 = kbase + (tn1r < ntiles ? tn1r : ntiles - 1);

        // ph1
        BARRIER(); LGKM0();
        MM(b0, 0, 0);
        READ_B1(0);

        // ph2
        BARRIER(); LGKM0();
        STAGE_B(0, 0, tn0);            // B0 last read-issue: prev ph8
        MM(b1, 0, 2);
        READ_A(0, 1);

        // ph3
        BARRIER(); LGKM0();
        STAGE_B(0, 1, tn0);            // B1 last read-issue: ph1
        MM(b1, 4, 2);

        // ph4
        BARRIER(); LGKM0();
        STAGE_A(0, 0, tn0); STAGE_A(0, 1, tn0);  // A last read-issue: ph2
        MM(b0, 4, 0);
        VMW8();                        // drains prev-iter buf1 stages (lead 4 phases)
        READ_A(1, 0); READ_B0(1);

        // ph5
        BARRIER(); LGKM0();
        MM(b0, 0, 0);
        READ_B1(1);

        // ph6
        BARRIER(); LGKM0();
        STAGE_B(1, 0, tn1);
        MM(b1, 0, 2);
        READ_A(1, 1);

        // ph7
        BARRIER(); LGKM0();
        STAGE_B(1, 1, tn1);
        MM(b1, 4, 2);

        // ph8
        BARRIER(); LGKM0();
        STAGE_A(1, 0, tn1); STAGE_A(1, 1, tn1);
        MM(b0, 4, 0);
        VMW8();                        // drains this-iter buf0 stages (lead 4 phases)
        READ_A(0, 0); READ_B0(0);
    }

    // ---- epilogue ----
    float bb[4];
    #pragma unroll
    for (int n = 0; n < 4; ++n)
        bb[n] = (MODE == 3) ? 0.0f : bias[bcol + (wc << 6) + (n << 4) + (lane & 15)];

    const int erow0 = brow + (wr << 7) + ((lane >> 4) << 2);
    const int ecol0 = bcol + (wc << 6) + (lane & 15);

    #pragma unroll
    for (int m = 0; m < 8; ++m) {
        #pragma unroll
        for (int i = 0; i < 4; ++i) {
            const int r = erow0 + (m << 4) + i;
            #pragma unroll
            for (int n = 0; n < 4; ++n) {
                const int c = ecol0 + (n << 4);
                float v = acc[m][n][i] + bb[n];
                if (MODE == 0) {
                    v = v > 0.0f ? v : 0.0f;
                    obf[(size_t)r * N + c] = f2bf_bits(v);
                } else {
                    pout[(size_t)r * N + c] = v;
                }
            }
        }
    }
#undef STAGE_A
#undef STAGE_B
#undef READ_A
#undef READ_B0
#undef READ_B1
#undef MM
}

// ---------- launch ----------
extern "C" void kernel_launch(void* const* d_in, const int* in_sizes, int n_in,
                              void* d_out, int out_size, void* d_ws, size_t ws_size,
                              hipStream_t stream) {
    const float* x   = (const float*)d_in[0];
    const float* We1 = (const float*)d_in[1];
    const float* be1 = (const float*)d_in[2];
    const float* We2 = (const float*)d_in[3];
    const float* be2 = (const float*)d_in[4];
    const float* Wd1 = (const float*)d_in[5];
    const float* bd1 = (const float*)d_in[6];
    const float* Wd2 = (const float*)d_in[7];
    const float* bd2 = (const float*)d_in[8];
    const float* eps = (const float*)d_in[9];

    const int B = 4096, D = 4096, H = 4096, LAT = 512;

    // workspace layout (lifetimes traced, same as round 9):
    //   [0, 33.5M)      xb (dead after G1) -> partials p0,p1 -> hd
    //   [33.5M, 67.1M)  w1t (dead after G1) -> partials p2,p3
    //   [67.1M, 75.5M)  w2t  [75.5M, 79.7M) w3t  [79.7M, 113.2M) w4t
    //   [113.2M,146.8M) h (dead after z-GEMM) -> zs at its start
    char* ws = (char*)d_ws;
    u16*   xb   = (u16*)(ws);
    u16*   w1t  = (u16*)(ws + 33554432);
    u16*   w2t  = (u16*)(ws + 67108864);
    u16*   w3t  = (u16*)(ws + 75497472);
    u16*   w4t  = (u16*)(ws + 79691776);
    u16*   h    = (u16*)(ws + 113246208);
    float* part = (float*)(ws);                 // 4 x (4096x1024) f32
    u16*   zs   = (u16*)(ws + 113246208);       // over dead h
    u16*   hd   = (u16*)(ws);                   // over dead partials

    float* recon = (float*)d_out;
    float* mu    = recon + (size_t)B * D;
    float* lv    = mu + (size_t)B * LAT;

    hipFuncSetAttribute(reinterpret_cast<const void*>(gemm256<0>),
                        hipFuncAttributeMaxDynamicSharedMemorySize, 131072);
    hipFuncSetAttribute(reinterpret_cast<const void*>(gemm256<1>),
                        hipFuncAttributeMaxDynamicSharedMemorySize, 131072);
    hipFuncSetAttribute(reinterpret_cast<const void*>(gemm256<3>),
                        hipFuncAttributeMaxDynamicSharedMemorySize, 131072);

    // fused preprocessing: 9728 transpose blocks + 16384 cvt blocks
    prep<<<26112, 256, 0, stream>>>(x, xb, We1, w1t, We2, w2t, Wd1, w3t, Wd2, w4t);

    // G1: h = relu(x @ We1 + be1)    M=B, N=H, K=D, 64 tiles
    gemm256<0><<<(B / 256) * (H / 256), 512, 131072, stream>>>(
        xb, w1t, be1, h, nullptr, B, H, D, D / 64);
    // z split-K=4: partials = h @ We2 (16 tiles per sid)
    gemm256<3><<<(B / 256) * (2 * LAT / 256) * 4, 512, 131072, stream>>>(
        h, w2t, nullptr, nullptr, part, B, 2 * LAT, H, (H / 64) / 4);
    // reduce + bias + sampler
    zred<<<(B * LAT / 4) / 256, 256, 0, stream>>>(part, be2, eps, mu, lv, zs);
    // G3: hd = relu(zs @ Wd1 + bd1)  M=B, N=H, K=LAT, 8 tiles
    gemm256<0><<<(B / 256) * (H / 256), 512, 131072, stream>>>(
        zs, w3t, bd1, hd, nullptr, B, H, LAT, LAT / 64);
    // G5: recon = hd @ Wd2 + bd2     M=B, N=D, K=H, 64 tiles
    gemm256<1><<<(B / 256) * (D / 256), 512, 131072, stream>>>(
        hd, w4t, bd2, nullptr, recon, B, D, H, H / 64);
}

// Round 14
// 347.612 us; speedup vs baseline: 1.2956x; 1.0209x over previous
//
#include <hip/hip_runtime.h>
#include <hip/hip_bf16.h>

typedef __attribute__((ext_vector_type(8))) __bf16 bf16x8;
typedef __attribute__((ext_vector_type(4))) float f32x4;
typedef __attribute__((ext_vector_type(4))) unsigned short ushort4v;
typedef __attribute__((ext_vector_type(8))) unsigned short ushort8v;
typedef unsigned short u16;

// ---------- helpers ----------
__device__ __forceinline__ u16 f2bf_bits(float f) {
    union { float f; unsigned int u; } x; x.f = f;
    unsigned int r = x.u + 0x7FFFu + ((x.u >> 16) & 1u);   // RNE
    return (u16)(r >> 16);
}

__device__ __forceinline__ float bf2f(u16 u) {
    union { unsigned int i; float f; } x; x.i = ((unsigned)u) << 16; return x.f;
}

__device__ __forceinline__ void gload_lds16(const void* g, void* l) {
    __builtin_amdgcn_global_load_lds(
        (const __attribute__((address_space(1))) void*)g,
        (__attribute__((address_space(3))) void*)l, 16, 0, 0);
}

#define BARRIER()  __builtin_amdgcn_s_barrier()
#define LGKM0()    asm volatile("s_waitcnt lgkmcnt(0)" ::: "memory")
#define VMW8()     asm volatile("s_waitcnt vmcnt(8)" ::: "memory")

// ---------- fused preprocessing: x cvt + 4 weight transpose-cvts ----------
__global__ __launch_bounds__(256)
void prep(const float* __restrict__ x,   u16* __restrict__ xb,
          const float* __restrict__ We1, u16* __restrict__ w1t,
          const float* __restrict__ We2, u16* __restrict__ w2t,
          const float* __restrict__ Wd1, u16* __restrict__ w3t,
          const float* __restrict__ Wd2, u16* __restrict__ w4t) {
    int bid = blockIdx.x;

    if (bid >= 9728) {                       // ---- cvt region: x -> xb (16M elems)
        const int i = ((bid - 9728) << 10) + ((int)threadIdx.x << 2);
        f32x4 v = *reinterpret_cast<const f32x4*>(x + i);
        ushort4v o;
        o.x = f2bf_bits(v.x); o.y = f2bf_bits(v.y);
        o.z = f2bf_bits(v.z); o.w = f2bf_bits(v.w);
        *reinterpret_cast<ushort4v*>(xb + i) = o;
        return;
    }

    const float* in; u16* out; int R, C, bx, by;
    if (bid < 4096)      { in = We1; out = w1t; R = 4096; C = 4096; bx = bid & 63; by = bid >> 6; }
    else if (bid < 5120) { bid -= 4096; in = We2; out = w2t; R = 4096; C = 1024; bx = bid & 15; by = bid >> 4; }
    else if (bid < 5632) { bid -= 5120; in = Wd1; out = w3t; R = 512;  C = 4096; bx = bid & 63; by = bid >> 6; }
    else                 { bid -= 5632; in = Wd2; out = w4t; R = 4096; C = 4096; bx = bid & 63; by = bid >> 6; }

    __shared__ float t[64][67];
    const int c0 = bx << 6;
    const int r0 = by << 6;
    const int tx = threadIdx.x & 15;
    const int ty = threadIdx.x >> 4;
    #pragma unroll
    for (int j = 0; j < 4; ++j) {
        f32x4 v = *reinterpret_cast<const f32x4*>(
            &in[(size_t)(r0 + ty + 16 * j) * C + c0 + (tx << 2)]);
        *reinterpret_cast<f32x4*>(&t[ty + 16 * j][tx << 2]) = v;
    }
    __syncthreads();
    const int orow8 = threadIdx.x >> 3;
    const int seg8  = (threadIdx.x & 7) << 3;
    #pragma unroll
    for (int p = 0; p < 2; ++p) {
        const int oc = orow8 + (p << 5);
        ushort8v o;
        #pragma unroll
        for (int i = 0; i < 8; ++i)
            o[i] = f2bf_bits(t[seg8 + i][oc]);
        *reinterpret_cast<ushort8v*>(&out[(size_t)(c0 + oc) * R + r0 + seg8]) = o;
    }
}

// ---------- split-K reduce (bf16 partials) + bias + reparameterization ----------
__global__ __launch_bounds__(256)
void zred(const u16* __restrict__ P, const float* __restrict__ be2,
          const float* __restrict__ eps, float* __restrict__ mu,
          float* __restrict__ lv, u16* __restrict__ zs) {
    const int i = blockIdx.x * 256 + threadIdx.x;      // over 4096*512/4
    const int r = i >> 7;
    const int c4 = (i & 127) << 2;
    const size_t base = (size_t)r * 1024 + c4;
    const size_t PS = (size_t)4096 * 1024;

    f32x4 m = (f32x4)(0.0f);
    f32x4 l = (f32x4)(0.0f);
    #pragma unroll
    for (int s = 0; s < 4; ++s) {
        ushort4v pm = *reinterpret_cast<const ushort4v*>(P + s * PS + base);
        ushort4v pl = *reinterpret_cast<const ushort4v*>(P + s * PS + base + 512);
        m.x += bf2f(pm.x); m.y += bf2f(pm.y); m.z += bf2f(pm.z); m.w += bf2f(pm.w);
        l.x += bf2f(pl.x); l.y += bf2f(pl.y); l.z += bf2f(pl.z); l.w += bf2f(pl.w);
    }
    m += *reinterpret_cast<const f32x4*>(be2 + c4);
    l += *reinterpret_cast<const f32x4*>(be2 + 512 + c4);

    const size_t ob = (size_t)r * 512 + c4;
    *reinterpret_cast<f32x4*>(mu + ob) = m;
    *reinterpret_cast<f32x4*>(lv + ob) = l;

    f32x4 e = *reinterpret_cast<const f32x4*>(eps + ob);
    ushort4v o;
    o.x = f2bf_bits(m.x + __expf(0.5f * l.x) * e.x);
    o.y = f2bf_bits(m.y + __expf(0.5f * l.y) * e.y);
    o.z = f2bf_bits(m.z + __expf(0.5f * l.z) * e.z);
    o.w = f2bf_bits(m.w + __expf(0.5f * l.w) * e.w);
    *reinterpret_cast<ushort4v*>(zs + ob) = o;
}

// ---------- 256x256 8-phase GEMM (r9 schedule, 16x16x32) ----------
// MODE 0: relu->bf16 obf. MODE 1: f32 of32. MODE 3: split-K bf16 partial
// (written to obf + sid*M*N), no bias.
// PRIO: 1 = wrap MM in s_setprio (r9 behavior); 0 = no setprio, letting the
// scheduler interleave next-phase ds_reads among the MFMAs (A/B experiment:
// G1 runs PRIO=0, G5 runs PRIO=1).
template<int MODE, int PRIO>
__global__ __launch_bounds__(512, 2)
void gemm256(const u16* __restrict__ A, const u16* __restrict__ Bt,
             const float* __restrict__ bias,
             u16* __restrict__ obf, float* __restrict__ of32,
             int M, int N, int K, int ntiles)
{
    extern __shared__ char lds[];
    const int tid  = threadIdx.x;
    const int lane = tid & 63;
    const int w    = tid >> 6;
    const int wr   = w >> 2;
    const int wc   = w & 3;

    int bid = blockIdx.x;
    int sid = 0;
    int nwg = gridDim.x;
    if (MODE == 3) { sid = bid & 3; bid >>= 2; nwg >>= 2; }
    const int cpx = nwg >> 3;
    bid = (bid & 7) * cpx + (bid >> 3);
    const int nbx  = N >> 8;
    const int brow = (bid / nbx) << 8;
    const int bcol = (bid % nbx) << 8;
    const int kbase = (MODE == 3) ? sid * ntiles : 0;
    u16* pp = (MODE == 3) ? obf + (size_t)sid * M * N : obf;

    const int srow  = tid >> 3;
    const int scole = (((tid & 7) ^ (srow & 7)) << 4) >> 1;
    const size_t aoff = (size_t)(brow + srow) * K + scole;
    const size_t boff = (size_t)(bcol + srow) * K + scole;
    const size_t rowK64 = (size_t)64 * K;
    const int wave1024 = w << 10;

    const int lo16 = (lane >> 4) << 4;
    const int swzm = (lane & 7) << 4;
    const int low0 = lo16 ^ swzm;
    const int low1 = (64 | lo16) ^ swzm;
    const int rA   = (lane & 15) << 7;
    const int rB   = ((((wc & 1) << 6) | (lane & 15)) << 7);
    const int regA = wr << 14;
    const int regB = 32768 + ((wc >> 1) << 14);

    bf16x8 a[4][2];
    bf16x8 b0[2][2];
    bf16x8 b1[2][2];
    f32x4 acc[8][4];
    #pragma unroll
    for (int m = 0; m < 8; ++m)
        #pragma unroll
        for (int n = 0; n < 4; ++n)
            acc[m][n] = (f32x4)(0.0f);

#define STAGE_A(buf, h, kt) do { \
    const u16* _s = A + aoff + (size_t)(h) * 128 * K + (size_t)(kt) * 64; \
    gload_lds16(_s,          lds + ((buf) << 16) + ((h) << 14) + wave1024); \
    gload_lds16(_s + rowK64, lds + ((buf) << 16) + ((h) << 14) + 8192 + wave1024); \
} while (0)

#define STAGE_B(buf, h, kt) do { \
    const u16* _s = Bt + boff + (size_t)(h) * 128 * K + (size_t)(kt) * 64; \
    gload_lds16(_s,          lds + ((buf) << 16) + 32768 + ((h) << 14) + wave1024); \
    gload_lds16(_s + rowK64, lds + ((buf) << 16) + 32768 + ((h) << 14) + 8192 + wave1024); \
} while (0)

#define READ_A(buf, g) do { \
    _Pragma("unroll") \
    for (int m = 0; m < 4; ++m) { \
        const int _b = ((buf) << 16) + regA + rA + ((((g) << 2) + m) << 11); \
        a[m][0] = *reinterpret_cast<const bf16x8*>(lds + _b + low0); \
        a[m][1] = *reinterpret_cast<const bf16x8*>(lds + _b + low1); \
    } \
} while (0)

#define READ_B0(buf) do { \
    _Pragma("unroll") \
    for (int n = 0; n < 2; ++n) { \
        const int _b = ((buf) << 16) + regB + rB + (n << 11); \
        b0[n][0] = *reinterpret_cast<const bf16x8*>(lds + _b + low0); \
        b0[n][1] = *reinterpret_cast<const bf16x8*>(lds + _b + low1); \
    } \
} while (0)

#define READ_B1(buf) do { \
    _Pragma("unroll") \
    for (int n = 0; n < 2; ++n) { \
        const int _b = ((buf) << 16) + regB + rB + ((n + 2) << 11); \
        b1[n][0] = *reinterpret_cast<const bf16x8*>(lds + _b + low0); \
        b1[n][1] = *reinterpret_cast<const bf16x8*>(lds + _b + low1); \
    } \
} while (0)

#define MM(bx, mb, nb) do { \
    if (PRIO) __builtin_amdgcn_s_setprio(1); \
    _Pragma("unroll") \
    for (int m = 0; m < 4; ++m) \
        _Pragma("unroll") \
        for (int n = 0; n < 2; ++n) \
            _Pragma("unroll") \
            for (int s = 0; s < 2; ++s) \
                acc[(mb) + m][(nb) + n] = __builtin_amdgcn_mfma_f32_16x16x32_bf16( \
                    a[m][s], bx[n][s], acc[(mb) + m][(nb) + n], 0, 0, 0); \
    if (PRIO) __builtin_amdgcn_s_setprio(0); \
} while (0)

    const int NIT = ntiles >> 1;   // 2 K-tiles of 64 per iteration

    // ---- prologue: tile kbase -> buf0, kbase+1 -> buf1 ----
    STAGE_A(0, 0, kbase); STAGE_A(0, 1, kbase); STAGE_B(0, 0, kbase); STAGE_B(0, 1, kbase);
    STAGE_A(1, 0, kbase + 1); STAGE_A(1, 1, kbase + 1); STAGE_B(1, 0, kbase + 1); STAGE_B(1, 1, kbase + 1);
    VMW8(); BARRIER();
    READ_A(0, 0); READ_B0(0);          // ph1 operands

    for (int it = 0; it < NIT; ++it) {
        const int tn0r = 2 * it + 2;
        const int tn1r = 2 * it + 3;
        const int tn0 = kbase + (tn0r < ntiles ? tn0r : ntiles - 1);  // dead-stage clamp
        const int tn1 = kbase + (tn1r < ntiles ? tn1r : ntiles - 1);

        // ph1
        BARRIER(); LGKM0();
        MM(b0, 0, 0);
        READ_B1(0);

        // ph2
        BARRIER(); LGKM0();
        STAGE_B(0, 0, tn0);            // B0 last read-issue: prev ph8
        MM(b1, 0, 2);
        READ_A(0, 1);

        // ph3
        BARRIER(); LGKM0();
        STAGE_B(0, 1, tn0);            // B1 last read-issue: ph1
        MM(b1, 4, 2);

        // ph4
        BARRIER(); LGKM0();
        STAGE_A(0, 0, tn0); STAGE_A(0, 1, tn0);  // A last read-issue: ph2
        MM(b0, 4, 0);
        VMW8();                        // drains prev-iter buf1 stages (lead 4 phases)
        READ_A(1, 0); READ_B0(1);

        // ph5
        BARRIER(); LGKM0();
        MM(b0, 0, 0);
        READ_B1(1);

        // ph6
        BARRIER(); LGKM0();
        STAGE_B(1, 0, tn1);
        MM(b1, 0, 2);
        READ_A(1, 1);

        // ph7
        BARRIER(); LGKM0();
        STAGE_B(1, 1, tn1);
        MM(b1, 4, 2);

        // ph8
        BARRIER(); LGKM0();
        STAGE_A(1, 0, tn1); STAGE_A(1, 1, tn1);
        MM(b0, 4, 0);
        VMW8();                        // drains this-iter buf0 stages (lead 4 phases)
        READ_A(0, 0); READ_B0(0);
    }

    // ---- epilogue ----
    float bb[4];
    #pragma unroll
    for (int n = 0; n < 4; ++n)
        bb[n] = (MODE == 3) ? 0.0f : bias[bcol + (wc << 6) + (n << 4) + (lane & 15)];

    const int erow0 = brow + (wr << 7) + ((lane >> 4) << 2);
    const int ecol0 = bcol + (wc << 6) + (lane & 15);

    #pragma unroll
    for (int m = 0; m < 8; ++m) {
        #pragma unroll
        for (int i = 0; i < 4; ++i) {
            const int r = erow0 + (m << 4) + i;
            #pragma unroll
            for (int n = 0; n < 4; ++n) {
                const int c = ecol0 + (n << 4);
                float v = acc[m][n][i] + bb[n];
                if (MODE == 0) {
                    v = v > 0.0f ? v : 0.0f;
                    obf[(size_t)r * N + c] = f2bf_bits(v);
                } else if (MODE == 3) {
                    pp[(size_t)r * N + c] = f2bf_bits(v);
                } else {
                    of32[(size_t)r * N + c] = v;
                }
            }
        }
    }
#undef STAGE_A
#undef STAGE_B
#undef READ_A
#undef READ_B0
#undef READ_B1
#undef MM
}

// ---------- launch ----------
extern "C" void kernel_launch(void* const* d_in, const int* in_sizes, int n_in,
                              void* d_out, int out_size, void* d_ws, size_t ws_size,
                              hipStream_t stream) {
    const float* x   = (const float*)d_in[0];
    const float* We1 = (const float*)d_in[1];
    const float* be1 = (const float*)d_in[2];
    const float* We2 = (const float*)d_in[3];
    const float* be2 = (const float*)d_in[4];
    const float* Wd1 = (const float*)d_in[5];
    const float* bd1 = (const float*)d_in[6];
    const float* Wd2 = (const float*)d_in[7];
    const float* bd2 = (const float*)d_in[8];
    const float* eps = (const float*)d_in[9];

    const int B = 4096, D = 4096, H = 4096, LAT = 512;

    // workspace layout (lifetimes traced):
    //   [0, 33.5M)      xb (dead after G1) -> bf16 partials (4 x 8.39M) -> hd
    //   [33.5M, 67.1M)  w1t (dead after G1)
    //   [67.1M, 75.5M)  w2t  [75.5M, 79.7M) w3t  [79.7M, 113.2M) w4t
    //   [113.2M,146.8M) h (dead after z-GEMM) -> zs at its start
    char* ws = (char*)d_ws;
    u16*   xb    = (u16*)(ws);
    u16*   w1t   = (u16*)(ws + 33554432);
    u16*   w2t   = (u16*)(ws + 67108864);
    u16*   w3t   = (u16*)(ws + 75497472);
    u16*   w4t   = (u16*)(ws + 79691776);
    u16*   h     = (u16*)(ws + 113246208);
    u16*   part  = (u16*)(ws);                  // 4 x (4096x1024) bf16 = 33.5 MB
    u16*   zs    = (u16*)(ws + 113246208);      // over dead h
    u16*   hd    = (u16*)(ws);                  // over dead partials

    float* recon = (float*)d_out;
    float* mu    = recon + (size_t)B * D;
    float* lv    = mu + (size_t)B * LAT;

    hipFuncSetAttribute(reinterpret_cast<const void*>(gemm256<0, 0>),
                        hipFuncAttributeMaxDynamicSharedMemorySize, 131072);
    hipFuncSetAttribute(reinterpret_cast<const void*>(gemm256<0, 1>),
                        hipFuncAttributeMaxDynamicSharedMemorySize, 131072);
    hipFuncSetAttribute(reinterpret_cast<const void*>(gemm256<1, 1>),
                        hipFuncAttributeMaxDynamicSharedMemorySize, 131072);
    hipFuncSetAttribute(reinterpret_cast<const void*>(gemm256<3, 1>),
                        hipFuncAttributeMaxDynamicSharedMemorySize, 131072);

    // fused preprocessing: 9728 transpose blocks + 16384 cvt blocks
    prep<<<26112, 256, 0, stream>>>(x, xb, We1, w1t, We2, w2t, Wd1, w3t, Wd2, w4t);

    // G1: h = relu(x @ We1 + be1)  — PRIO=0 (A/B experiment arm)
    gemm256<0, 0><<<(B / 256) * (H / 256), 512, 131072, stream>>>(
        xb, w1t, be1, h, nullptr, B, H, D, D / 64);
    // z split-K=4: bf16 partials = h @ We2 (16 tiles per sid)
    gemm256<3, 1><<<(B / 256) * (2 * LAT / 256) * 4, 512, 131072, stream>>>(
        h, w2t, nullptr, part, nullptr, B, 2 * LAT, H, (H / 64) / 4);
    // reduce + bias + sampler
    zred<<<(B * LAT / 4) / 256, 256, 0, stream>>>(part, be2, eps, mu, lv, zs);
    // G3: hd = relu(zs @ Wd1 + bd1)  — PRIO=1
    gemm256<0, 1><<<(B / 256) * (H / 256), 512, 131072, stream>>>(
        zs, w3t, bd1, hd, nullptr, B, H, LAT, LAT / 64);
    // G5: recon = hd @ Wd2 + bd2   — PRIO=1 (control arm)
    gemm256<1, 1><<<(B / 256) * (D / 256), 512, 131072, stream>>>(
        hd, w4t, bd2, nullptr, recon, B, D, H, H / 64);
}